// Round 11
// baseline (202.673 us; speedup 1.0000x reference)
//
#include <hip/hip_runtime.h>
#include <stdint.h>

typedef unsigned short u16;
typedef __attribute__((ext_vector_type(8))) short v8s;
typedef __attribute__((ext_vector_type(4))) float v4f;

// ---------- helpers ----------
__device__ __forceinline__ u16 f2bf(float f) {
  uint32_t x = __float_as_uint(f);
  return (u16)((x + 0x7fffu + ((x >> 16) & 1u)) >> 16);
}
__device__ __forceinline__ float bf2f(u16 u) {
  return __uint_as_float(((uint32_t)u) << 16);
}
__device__ __forceinline__ float sigf(float x) { return 1.f / (1.f + __expf(-x)); }
// fast tanh: |err| ~1e-6, far below bf16 quantization
__device__ __forceinline__ float tanhf_fast(float x) {
  float e = __expf(-2.f * fabsf(x));
  float r = (1.f - e) / (1.f + e);
  return copysignf(r, x);
}

__device__ __forceinline__ v4f mfma16(v8s a, v8s b, v4f c) {
  return __builtin_amdgcn_mfma_f32_16x16x32_bf16(a, b, c, 0, 0, 0);
}

// async global->LDS, 16B/lane; LDS dest wave-uniform (HW adds lane*16)
__device__ __forceinline__ void gll16(const u16* src, u16* ldsdst) {
  __builtin_amdgcn_global_load_lds(
      reinterpret_cast<__attribute__((address_space(1))) uint32_t*>(
          reinterpret_cast<uintptr_t>(src)),
      reinterpret_cast<__attribute__((address_space(3))) uint32_t*>(
          reinterpret_cast<uintptr_t>(ldsdst)),
      16, 0, 0);
}

// Fragment-packed (FP) layout for bf16 matrix M[R][K] (R%16==0, K%64==0, KT=K/64):
// chunk s of tile (tr,tk), lane l (= q*16+r) holds M[tr*16+r][tk*64+s*32+q*8 ..+7].
__device__ __forceinline__ size_t fpoff(int row, int k, int KT) {
  return ((size_t)(((row >> 4) * KT + (k >> 6)) * 2 + ((k >> 5) & 1)) * 64 +
          ((k >> 3) & 3) * 16 + (row & 15)) * 8 + (k & 7);
}

__device__ __forceinline__ void load8(const float* p, float* f) {
  float4 a = *(const float4*)p;
  float4 b = *(const float4*)(p + 4);
  f[0]=a.x; f[1]=a.y; f[2]=a.z; f[3]=a.w; f[4]=b.x; f[5]=b.y; f[6]=b.z; f[7]=b.w;
}
__device__ __forceinline__ void store8bf(u16* dst, const float* f) {
  u16 t[8];
#pragma unroll
  for (int i = 0; i < 8; ++i) t[i] = f2bf(f[i]);
  *(v8s*)dst = *(const v8s*)t;
}

// ---------- kernel 1: fused zero-flags + convert/pack + mean pass 1 ----------
// blocks 0..5951 convert; 5952..7999 mean pass1; 8000..8015 zero flags+slots
__global__ __launch_bounds__(256) void k_convert_mean(
    const float* __restrict__ Wh, const float* __restrict__ Wm,
    const float* __restrict__ Wih, const float* __restrict__ Whh,
    const float* __restrict__ Wfc, const float* __restrict__ label,
    const float* __restrict__ image,
    u16* __restrict__ wcomb, u16* __restrict__ whhb, u16* __restrict__ wfcb,
    u16* __restrict__ wlabb, u16* __restrict__ labb,
    float4* __restrict__ pacc, unsigned* __restrict__ ctr) {
  const int bid = blockIdx.x, tid = threadIdx.x;
  if (bid >= 8000) {  // zero flags (3840) + xcd slot counters (8) + spare
    ctr[(bid - 8000) * 256 + tid] = 0u;
    return;
  }
  if (bid >= 5952) {  // mean pass 1: 2048 blocks = b(256) x oct(8)
    int bi = bid - 5952;
    int b = bi >> 3, oct = bi & 7;
    const float4* src =
        (const float4*)image + (size_t)b * 65536 + (size_t)oct * 32 * 256 + tid;
    float4 s = make_float4(0.f, 0.f, 0.f, 0.f);
#pragma unroll 8
    for (int ss = 0; ss < 32; ++ss) {
      float4 v = src[(size_t)ss * 256];
      s.x += v.x; s.y += v.y; s.z += v.z; s.w += v.w;
    }
    pacc[(size_t)bi * 256 + tid] = s;
    return;
  }
  int64_t u = (int64_t)bid * 256 + tid;
  float f[8];
  if (u < 786432) {  // wcomb, KT=16
    int lu = (int)u;
    int r15 = lu & 15, q = (lu >> 4) & 3, s = (lu >> 6) & 1, tile = lu >> 7;
    int tk = tile & 15, tr = tile >> 4;
    int row = tr * 16 + r15, k = tk * 64 + s * 32 + q * 8;
    if (row < 1024) load8(Wh + (size_t)row * 1024 + k, f);
    else if (row < 2048) load8(Wm + (size_t)(row - 1024) * 1024 + k, f);
    else {
      const float* p = Wih + (size_t)(row - 2048) * 1097 + k;
#pragma unroll
      for (int i = 0; i < 8; ++i) f[i] = p[i];
    }
    store8bf(wcomb + (size_t)lu * 8, f);
  } else if (u < 1310720) {  // whhb, KT=16
    int lu = (int)(u - 786432);
    int r15 = lu & 15, q = (lu >> 4) & 3, s = (lu >> 6) & 1, tile = lu >> 7;
    int tk = tile & 15, tr = tile >> 4;
    int row = tr * 16 + r15, k = tk * 64 + s * 32 + q * 8;
    load8(Whh + (size_t)row * 1024 + k, f);
    store8bf(whhb + (size_t)lu * 8, f);
  } else if (u < 1458176) {  // wfcb, KT=16, rows>=1090 zero
    int lu = (int)(u - 1310720);
    int r15 = lu & 15, q = (lu >> 4) & 3, s = (lu >> 6) & 1, tile = lu >> 7;
    int tk = tile & 15, tr = tile >> 4;
    int row = tr * 16 + r15, k = tk * 64 + s * 32 + q * 8;
    if (row < 1090) load8(Wfc + (size_t)row * 1024 + k, f);
    else {
#pragma unroll
      for (int i = 0; i < 8; ++i) f[i] = 0.f;
    }
    store8bf(wfcb + (size_t)lu * 8, f);
  } else if (u < 1490944) {  // wlabb, KT=1
    int lu = (int)(u - 1458176);
    int r15 = lu & 15, q = (lu >> 4) & 3, s = (lu >> 6) & 1, tile = lu >> 7;
    int row = tile * 16 + r15, k = s * 32 + q * 8;
    const float* p = Wih + (size_t)row * 1097 + 1033 + k;
#pragma unroll
    for (int i = 0; i < 8; ++i) f[i] = p[i];
    store8bf(wlabb + (size_t)lu * 8, f);
  } else {  // labb, KT=1, row=t*256+b
    int lu = (int)(u - 1490944);
    int r15 = lu & 15, q = (lu >> 4) & 3, s = (lu >> 6) & 1, tile = lu >> 7;
    int row = tile * 16 + r15, k = s * 32 + q * 8;
    int t = row >> 8, b = row & 255;
    load8(label + ((size_t)b * 17 + t) * 64 + k, f);
    store8bf(labb + (size_t)lu * 8, f);
  }
}

// ---------- kernel 2: mean pass 2 ----------
__global__ __launch_bounds__(256) void k_mean2(const float4* __restrict__ pacc,
                                               u16* __restrict__ meanbf) {
  int b = blockIdx.x, tid = threadIdx.x;
  float4 s = make_float4(0.f, 0.f, 0.f, 0.f);
#pragma unroll
  for (int q = 0; q < 8; ++q) {
    float4 v = pacc[((size_t)b * 8 + q) * 256 + tid];
    s.x += v.x; s.y += v.y; s.z += v.z; s.w += v.w;
  }
  const float inv = 1.f / 256.f;
  int k = tid * 4;
  ushort4 o;
  o.x = f2bf(s.x * inv); o.y = f2bf(s.y * inv);
  o.z = f2bf(s.z * inv); o.w = f2bf(s.w * inv);
  *(ushort4*)&meanbf[fpoff(b, k, 16)] = o;
}

// ---------- kernel 3: mean @ [Wh|Wm|Wih_E]^T -> h0(FP bf16), m0(f32), base(f32) ----------
__global__ __launch_bounds__(256) void k_gemm_init(
    const u16* __restrict__ meanbf, const u16* __restrict__ wcomb,
    const float* __restrict__ bh, const float* __restrict__ bm,
    const float* __restrict__ bih, const float* __restrict__ bhh,
    const float* __restrict__ vp, const float* __restrict__ Wih,
    u16* __restrict__ hbuf, float* __restrict__ mbuf, float* __restrict__ basebuf) {
  __shared__ alignas(16) u16 lA[4 * 1024];
  __shared__ alignas(16) u16 lB[4 * 1024];
  const int tid = threadIdx.x, lane = tid & 63, wid = tid >> 6;
  const int bm0 = (blockIdx.x & 3) * 64;
  const int bn0 = (blockIdx.x >> 2) * 64;  // grid 4*96
  const int wr = wid >> 1, wc = wid & 1;
  v4f acc[2][2];
#pragma unroll
  for (int i = 0; i < 2; ++i)
#pragma unroll
    for (int j = 0; j < 2; ++j) acc[i][j] = (v4f){0.f, 0.f, 0.f, 0.f};

  for (int kt = 0; kt < 16; ++kt) {
    const u16* asrc = meanbf + ((size_t)((bm0 >> 4) + wid) * 16 + kt) * 1024 + lane * 8;
    gll16(asrc, lA + wid * 1024);
    gll16(asrc + 512, lA + wid * 1024 + 512);
    const u16* bsrc = wcomb + ((size_t)((bn0 >> 4) + wid) * 16 + kt) * 1024 + lane * 8;
    gll16(bsrc, lB + wid * 1024);
    gll16(bsrc + 512, lB + wid * 1024 + 512);
    __syncthreads();
#pragma unroll
    for (int s = 0; s < 2; ++s) {
      v8s a0 = *(const v8s*)&lA[(size_t)(wr * 2) * 1024 + s * 512 + lane * 8];
      v8s a1 = *(const v8s*)&lA[(size_t)(wr * 2 + 1) * 1024 + s * 512 + lane * 8];
      v8s b0 = *(const v8s*)&lB[(size_t)(wc * 2) * 1024 + s * 512 + lane * 8];
      v8s b1 = *(const v8s*)&lB[(size_t)(wc * 2 + 1) * 1024 + s * 512 + lane * 8];
      acc[0][0] = mfma16(a0, b0, acc[0][0]);
      acc[0][1] = mfma16(a0, b1, acc[0][1]);
      acc[1][0] = mfma16(a1, b0, acc[1][0]);
      acc[1][1] = mfma16(a1, b1, acc[1][1]);
    }
    __syncthreads();
  }
#pragma unroll
  for (int fm = 0; fm < 2; ++fm)
#pragma unroll
    for (int fn = 0; fn < 2; ++fn)
#pragma unroll
      for (int rg = 0; rg < 4; ++rg) {
        int row = bm0 + wr * 32 + fm * 16 + ((lane >> 4) << 2) + rg;  // b
        int col = bn0 + wc * 32 + fn * 16 + (lane & 15);              // packed n
        float v = acc[fm][fn][rg];
        if (col < 1024) {
          hbuf[fpoff(row, col, 16)] = f2bf(tanhf_fast(v + bh[col]));
        } else if (col < 2048) {
          int nn = col - 1024;
          mbuf[(size_t)row * 1024 + nn] = tanhf_fast(v + bm[nn]);
        } else {
          int j = col - 2048;
          float sv = v + bih[j] + bhh[j];
#pragma unroll
          for (int q = 0; q < 8; ++q)
            sv += vp[row * 8 + q] * Wih[(size_t)j * 1097 + 1024 + q];
          basebuf[(size_t)row * 4096 + j] = sv;
        }
      }
}

// ---------- kernel 5: persistent 16-step LSTM, weight-stationary, XCD-local ----------
// grid 256 (1 block/CU: LDS 145KB), wave w = gate w. Runtime XCD discovery:
// grp = own XCC_ID (s_getreg hwreg20), n0idx = per-XCD atomic slot claim ->
// each comm group (32 blocks sharing b0-rows) is PROVABLY on one XCD.
// h handoff + flags use plain/volatile (L2-local) ops: L1 is write-through so
// plain stores land in the shared XCD L2; volatile (sc0) loads bypass L1.
// Any claim order is a valid permutation -> dispatch-independent correctness;
// hbuf[16] -> k_fc visibility via implicit end-of-kernel L2 writeback.
__global__ __launch_bounds__(256, 1) void k_steps(
    const u16* __restrict__ whhb, const u16* __restrict__ wlabb,
    const u16* __restrict__ labb, const float* __restrict__ basebuf,
    const float* __restrict__ Wih, const float* __restrict__ mbuf,
    u16* __restrict__ hbuf, unsigned* __restrict__ ctr) {
  __shared__ alignas(16) u16 lA[64 * 512];      // 64 KB: 64 FP chunks of h[t]
  __shared__ alignas(16) u16 lLab[64 * 512];    // 64 KB: lab tiles, all 16 steps
  __shared__ alignas(16) float lact[4][32 * 33];
  __shared__ int sGrp, sSlot;
  const int tid = threadIdx.x, lane = tid & 63, wid = tid >> 6;

  // XCD-local slot claim (one-time)
  if (tid == 0) {
    unsigned xcc;
    asm volatile("s_getreg_b32 %0, hwreg(20, 0, 32)" : "=s"(xcc));
    xcc &= 7u;
    unsigned slot = __hip_atomic_fetch_add(&ctr[3840 + xcc], 1u,
                                           __ATOMIC_RELAXED,
                                           __HIP_MEMORY_SCOPE_AGENT);
    sGrp = (int)xcc;
    sSlot = (int)(slot & 31u);
  }
  __syncthreads();
  const int grp = sGrp;                          // b0-group == own XCD
  const int n0idx = sSlot;                       // 0..31 within XCD
  const int n0 = n0idx * 32;
  const int b0 = grp * 32;
  const int atr = b0 >> 4;

  // stage ALL label tiles: chunk c=t*4+i*2+s -> labb tile (t*16+atr+i), chunk s
#pragma unroll
  for (int j = 0; j < 16; ++j) {
    const int c = wid * 16 + j;
    const int t = c >> 2, i = (c >> 1) & 1, s = c & 1;
    gll16(labb + (size_t)(t * 16 + atr + i) * 1024 + s * 512 + lane * 8,
          lLab + c * 512);
  }

  // B preload: gate wid, n-tiles tr0,tr0+1, all 16 k-tiles -> 64 v8s (regs/AGPRs)
  const int tr0 = wid * 64 + (n0 >> 4);
  v8s breg[16][2][2];
#pragma unroll
  for (int kt = 0; kt < 16; ++kt)
#pragma unroll
    for (int s = 0; s < 2; ++s)
#pragma unroll
      for (int j = 0; j < 2; ++j)
        breg[kt][s][j] =
            *(const v8s*)&whhb[((size_t)(tr0 + j) * 16 + kt) * 1024 + s * 512 + lane * 8];
  // Wlab slice: same tiles, KT=1
  v8s wlreg[2][2];
#pragma unroll
  for (int s = 0; s < 2; ++s)
#pragma unroll
    for (int j = 0; j < 2; ++j)
      wlreg[s][j] = *(const v8s*)&wlabb[(size_t)(tr0 + j) * 1024 + s * 512 + lane * 8];

  // per-thread state: thread -> (b0+rowm, n0+nql..+3)
  const int rowm = tid >> 3;
  const int nql = (tid & 7) * 4;
  const int b = b0 + rowm;
  const int n = n0 + nql;
  float4 mreg = *(const float4*)&mbuf[(size_t)b * 1024 + n];
  float4 bse[4], wbv[4];
#pragma unroll
  for (int g = 0; g < 4; ++g) {
    bse[g] = *(const float4*)&basebuf[(size_t)b * 4096 + g * 1024 + n];
#pragma unroll
    for (int q = 0; q < 4; ++q)
      ((float*)&wbv[g])[q] = Wih[(size_t)(g * 1024 + n + q) * 1097 + 1032];
  }
  __syncthreads();  // drains lLab gll16s + all preloads

  for (int t = 0; t < 16; ++t) {
    // wait for h[t] producers (same XCD; volatile = sc0 L1-bypass, L2 read)
    if (t > 0) {
      if (wid == 0) {
        const volatile unsigned* f = &ctr[((t - 1) * 8 + grp) * 32];
        for (int it = 0; it < (1 << 18); ++it) {
          unsigned v = f[lane & 31];
          if (__ballot(v == 0u) == 0ull) break;
          __builtin_amdgcn_s_sleep(1);
        }
      }
      __syncthreads();
    }
    const u16* hsrc = hbuf + (size_t)t * 262144;
    __builtin_amdgcn_sched_barrier(0);
    // h half0: per-wave chunks hc=wid*8+j -> (i=hc>>4, kt=(hc>>1)&7, s=hc&1)
#pragma unroll
    for (int j = 0; j < 8; ++j) {
      const int hc = wid * 8 + j;
      const int i = hc >> 4, kt = (hc >> 1) & 7, s = hc & 1;
      gll16(hsrc + ((size_t)(atr + i) * 16 + kt) * 1024 + s * 512 + lane * 8,
            lA + (i * 32 + kt * 2 + s) * 512);
    }
    __builtin_amdgcn_sched_barrier(0);
    // h half1: kt+8
#pragma unroll
    for (int j = 0; j < 8; ++j) {
      const int hc = wid * 8 + j;
      const int i = hc >> 4, kt = ((hc >> 1) & 7) + 8, s = hc & 1;
      gll16(hsrc + ((size_t)(atr + i) * 16 + kt) * 1024 + s * 512 + lane * 8,
            lA + (i * 32 + kt * 2 + s) * 512);
    }
    __builtin_amdgcn_sched_barrier(0);

    // bias GEMM: acc = lab[t] @ Wlab^T (LDS+reg only; hides stage latency)
    v4f acc[2][2];
#pragma unroll
    for (int i = 0; i < 2; ++i)
#pragma unroll
      for (int j = 0; j < 2; ++j) acc[i][j] = (v4f){0.f, 0.f, 0.f, 0.f};
#pragma unroll
    for (int s = 0; s < 2; ++s) {
      v8s aL0 = *(const v8s*)&lLab[(size_t)(t * 4 + 0 * 2 + s) * 512 + lane * 8];
      v8s aL1 = *(const v8s*)&lLab[(size_t)(t * 4 + 1 * 2 + s) * 512 + lane * 8];
      acc[0][0] = mfma16(aL0, wlreg[s][0], acc[0][0]);
      acc[0][1] = mfma16(aL0, wlreg[s][1], acc[0][1]);
      acc[1][0] = mfma16(aL1, wlreg[s][0], acc[1][0]);
      acc[1][1] = mfma16(aL1, wlreg[s][1], acc[1][1]);
    }

    __builtin_amdgcn_sched_barrier(0);
    asm volatile("s_waitcnt vmcnt(8)" ::: "memory");   // h half0 landed
    __builtin_amdgcn_sched_barrier(0);
    __builtin_amdgcn_s_barrier();
    __builtin_amdgcn_sched_barrier(0);
#pragma unroll
    for (int kt = 0; kt < 8; ++kt)
#pragma unroll
      for (int s = 0; s < 2; ++s) {
        v8s a0 = *(const v8s*)&lA[(size_t)((0 * 16 + kt) * 2 + s) * 512 + lane * 8];
        v8s a1 = *(const v8s*)&lA[(size_t)((1 * 16 + kt) * 2 + s) * 512 + lane * 8];
        acc[0][0] = mfma16(a0, breg[kt][s][0], acc[0][0]);
        acc[0][1] = mfma16(a0, breg[kt][s][1], acc[0][1]);
        acc[1][0] = mfma16(a1, breg[kt][s][0], acc[1][0]);
        acc[1][1] = mfma16(a1, breg[kt][s][1], acc[1][1]);
      }

    __builtin_amdgcn_sched_barrier(0);
    asm volatile("s_waitcnt vmcnt(0)" ::: "memory");   // h half1 landed
    __builtin_amdgcn_sched_barrier(0);
    __builtin_amdgcn_s_barrier();
    __builtin_amdgcn_sched_barrier(0);
#pragma unroll
    for (int kt = 8; kt < 16; ++kt)
#pragma unroll
      for (int s = 0; s < 2; ++s) {
        v8s a0 = *(const v8s*)&lA[(size_t)((0 * 16 + kt) * 2 + s) * 512 + lane * 8];
        v8s a1 = *(const v8s*)&lA[(size_t)((1 * 16 + kt) * 2 + s) * 512 + lane * 8];
        acc[0][0] = mfma16(a0, breg[kt][s][0], acc[0][0]);
        acc[0][1] = mfma16(a0, breg[kt][s][1], acc[0][1]);
        acc[1][0] = mfma16(a1, breg[kt][s][0], acc[1][0]);
        acc[1][1] = mfma16(a1, breg[kt][s][1], acc[1][1]);
      }

#pragma unroll
    for (int fm = 0; fm < 2; ++fm)
#pragma unroll
      for (int fn = 0; fn < 2; ++fn)
#pragma unroll
        for (int rg = 0; rg < 4; ++rg) {
          int rr = fm * 16 + ((lane >> 4) << 2) + rg;
          int cc = fn * 16 + (lane & 15);
          lact[wid][rr * 33 + cc] = acc[fm][fn][rg];
        }
    __syncthreads();

    // activations: gates = lact + base (+ W_begin at t=0)
    const float w0 = (t == 0) ? 1.f : 0.f;
    float m2a[4];
    u16 h2a[4];
#pragma unroll
    for (int q = 0; q < 4; ++q) {
      float gi = lact[0][rowm * 33 + nql + q] + ((const float*)&bse[0])[q] + w0 * ((const float*)&wbv[0])[q];
      float gf = lact[1][rowm * 33 + nql + q] + ((const float*)&bse[1])[q] + w0 * ((const float*)&wbv[1])[q];
      float gg = lact[2][rowm * 33 + nql + q] + ((const float*)&bse[2])[q] + w0 * ((const float*)&wbv[2])[q];
      float go = lact[3][rowm * 33 + nql + q] + ((const float*)&bse[3])[q] + w0 * ((const float*)&wbv[3])[q];
      float mov = ((const float*)&mreg)[q];
      float m2 = sigf(gf) * mov + sigf(gi) * tanhf_fast(gg);
      float h2 = sigf(go) * tanhf_fast(m2);
      m2a[q] = m2;
      h2a[q] = f2bf(h2);
    }
    mreg = make_float4(m2a[0], m2a[1], m2a[2], m2a[3]);
    ushort4 ho;
    ho.x = h2a[0]; ho.y = h2a[1]; ho.z = h2a[2]; ho.w = h2a[3];
    // plain 8B h-store: write-through L1 -> lands in the XCD-shared L2
    unsigned long long hv;
    __builtin_memcpy(&hv, &ho, 8);
    *reinterpret_cast<unsigned long long*>(
        &hbuf[(size_t)(t + 1) * 262144 + fpoff(b, n, 16)]) = hv;

    if (t < 15) {
      __syncthreads();  // drains vmcnt: all 4 waves' h-stores are in L2
      if (tid == 0) {   // per-producer flag: plain volatile store (L2-local)
        volatile unsigned* fw = &ctr[(t * 8 + grp) * 32 + n0idx];
        *fw = 1u;
      }
    }
  }
}

// ---------- kernel 6: batched FC + epilogue + mask ----------
__global__ __launch_bounds__(256) void k_fc(
    const u16* __restrict__ hall, const u16* __restrict__ wfcb,
    const float* __restrict__ bfc, const int* __restrict__ length,
    float* __restrict__ out) {
  __shared__ alignas(16) u16 lA[4 * 1024];
  __shared__ alignas(16) u16 lB[4 * 1024];
  const int tid = threadIdx.x, lane = tid & 63, wid = tid >> 6;
  const int bm0 = (int)(blockIdx.x % 64) * 64;
  const int bn0 = (int)(blockIdx.x / 64) * 64;  // grid 64*18
  const int wr = wid >> 1, wc = wid & 1;
  v4f acc[2][2];
#pragma unroll
  for (int i = 0; i < 2; ++i)
#pragma unroll
    for (int j = 0; j < 2; ++j) acc[i][j] = (v4f){0.f, 0.f, 0.f, 0.f};

  for (int kt = 0; kt < 16; ++kt) {
    const u16* asrc = hall + ((size_t)((bm0 >> 4) + wid) * 16 + kt) * 1024 + lane * 8;
    gll16(asrc, lA + wid * 1024);
    gll16(asrc + 512, lA + wid * 1024 + 512);
    const u16* bsrc = wfcb + ((size_t)((bn0 >> 4) + wid) * 16 + kt) * 1024 + lane * 8;
    gll16(bsrc, lB + wid * 1024);
    gll16(bsrc + 512, lB + wid * 1024 + 512);
    __syncthreads();
#pragma unroll
    for (int s = 0; s < 2; ++s) {
      v8s a0 = *(const v8s*)&lA[(size_t)(wr * 2) * 1024 + s * 512 + lane * 8];
      v8s a1 = *(const v8s*)&lA[(size_t)(wr * 2 + 1) * 1024 + s * 512 + lane * 8];
      v8s b0 = *(const v8s*)&lB[(size_t)(wc * 2) * 1024 + s * 512 + lane * 8];
      v8s b1 = *(const v8s*)&lB[(size_t)(wc * 2 + 1) * 1024 + s * 512 + lane * 8];
      acc[0][0] = mfma16(a0, b0, acc[0][0]);
      acc[0][1] = mfma16(a0, b1, acc[0][1]);
      acc[1][0] = mfma16(a1, b0, acc[1][0]);
      acc[1][1] = mfma16(a1, b1, acc[1][1]);
    }
    __syncthreads();
  }
#pragma unroll
  for (int fm = 0; fm < 2; ++fm)
#pragma unroll
    for (int fn = 0; fn < 2; ++fn)
#pragma unroll
      for (int rg = 0; rg < 4; ++rg) {
        int r = bm0 + wr * 32 + fm * 16 + ((lane >> 4) << 2) + rg;
        int j = bn0 + wc * 32 + fn * 16 + (lane & 15);
        if (j < 64 || j >= 1090) continue;
        int t = r >> 8, b = r & 255;
        float v = acc[fm][fn][rg] + bfc[j];
        int c;
        if (j < 1088) { c = j - 64; v = fmaxf(v, 0.f); }
        else if (j == 1088) { c = 1024; v = 1.f / (1.f + expf(-v)); }
        else { c = 1025; v = expf(v); }
        if (t >= length[b] - 1) v = 0.f;
        out[((size_t)t * 256 + b) * 1026 + c] = v;
      }
}

extern "C" void kernel_launch(void* const* d_in, const int* in_sizes, int n_in,
                              void* d_out, int out_size, void* d_ws, size_t ws_size,
                              hipStream_t stream) {
  (void)in_sizes; (void)n_in; (void)out_size; (void)ws_size;
  const float* image  = (const float*)d_in[0];
  const float* vp     = (const float*)d_in[1];
  const float* label  = (const float*)d_in[2];
  const int*   length = (const int*)d_in[3];
  const float* Wh  = (const float*)d_in[4];
  const float* bh  = (const float*)d_in[5];
  const float* Wm  = (const float*)d_in[6];
  const float* bm  = (const float*)d_in[7];
  const float* Wih = (const float*)d_in[8];
  const float* Whh = (const float*)d_in[9];
  const float* bih = (const float*)d_in[10];
  const float* bhh = (const float*)d_in[11];
  const float* Wfc = (const float*)d_in[12];
  const float* bfc = (const float*)d_in[13];
  float* out = (float*)d_out;
  char* ws = (char*)d_ws;

  size_t off = 0;
  u16* wcomb  = (u16*)(ws + off); off += (size_t)6144 * 1024 * 2;
  u16* whhb   = (u16*)(ws + off); off += (size_t)4096 * 1024 * 2;
  u16* wfcb   = (u16*)(ws + off); off += (size_t)1152 * 1024 * 2;
  u16* wlabb  = (u16*)(ws + off); off += (size_t)4096 * 64 * 2;
  u16* labb   = (u16*)(ws + off); off += (size_t)4096 * 64 * 2;
  u16* meanbf = (u16*)(ws + off); off += (size_t)256 * 1024 * 2;
  u16* hbuf   = (u16*)(ws + off); off += (size_t)17 * 256 * 1024 * 2;
  float* mbuf    = (float*)(ws + off); off += (size_t)256 * 1024 * 4;
  float* basebuf = (float*)(ws + off); off += (size_t)256 * 4096 * 4;
  unsigned* ctr = (unsigned*)(ws + off); off += 4096 * 4;
  float4* pacc = (float4*)(ws + off); off += (size_t)2048 * 256 * 16;

  k_convert_mean<<<8016, 256, 0, stream>>>(Wh, Wm, Wih, Whh, Wfc, label, image,
                                           wcomb, whhb, wfcb, wlabb, labb, pacc, ctr);
  k_mean2<<<256, 256, 0, stream>>>(pacc, meanbf);
  k_gemm_init<<<384, 256, 0, stream>>>(meanbf, wcomb, bh, bm, bih, bhh, vp, Wih,
                                       hbuf, mbuf, basebuf);
  k_steps<<<256, 256, 0, stream>>>(whhb, wlabb, labb, basebuf, Wih, mbuf, hbuf, ctr);
  k_fc<<<1152, 256, 0, stream>>>(hbuf + (size_t)256 * 1024, wfcb, bfc, length, out);
}

// Round 12
// 196.370 us; speedup vs baseline: 1.0321x; 1.0321x over previous
//
#include <hip/hip_runtime.h>
#include <stdint.h>

typedef unsigned short u16;
typedef __attribute__((ext_vector_type(8))) short v8s;
typedef __attribute__((ext_vector_type(4))) float v4f;

// ---------- helpers ----------
__device__ __forceinline__ u16 f2bf(float f) {
  uint32_t x = __float_as_uint(f);
  return (u16)((x + 0x7fffu + ((x >> 16) & 1u)) >> 16);
}
__device__ __forceinline__ float bf2f(u16 u) {
  return __uint_as_float(((uint32_t)u) << 16);
}
__device__ __forceinline__ float sigf(float x) { return 1.f / (1.f + __expf(-x)); }
// fast tanh: |err| ~1e-6, far below bf16 quantization
__device__ __forceinline__ float tanhf_fast(float x) {
  float e = __expf(-2.f * fabsf(x));
  float r = (1.f - e) / (1.f + e);
  return copysignf(r, x);
}

__device__ __forceinline__ v4f mfma16(v8s a, v8s b, v4f c) {
  return __builtin_amdgcn_mfma_f32_16x16x32_bf16(a, b, c, 0, 0, 0);
}

// async global->LDS, 16B/lane; LDS dest wave-uniform (HW adds lane*16)
__device__ __forceinline__ void gll16(const u16* src, u16* ldsdst) {
  __builtin_amdgcn_global_load_lds(
      reinterpret_cast<__attribute__((address_space(1))) uint32_t*>(
          reinterpret_cast<uintptr_t>(src)),
      reinterpret_cast<__attribute__((address_space(3))) uint32_t*>(
          reinterpret_cast<uintptr_t>(ldsdst)),
      16, 0, 0);
}

// Fragment-packed (FP) layout for bf16 matrix M[R][K] (R%16==0, K%64==0, KT=K/64):
// chunk s of tile (tr,tk), lane l (= q*16+r) holds M[tr*16+r][tk*64+s*32+q*8 ..+7].
__device__ __forceinline__ size_t fpoff(int row, int k, int KT) {
  return ((size_t)(((row >> 4) * KT + (k >> 6)) * 2 + ((k >> 5) & 1)) * 64 +
          ((k >> 3) & 3) * 16 + (row & 15)) * 8 + (k & 7);
}

__device__ __forceinline__ void load8(const float* p, float* f) {
  float4 a = *(const float4*)p;
  float4 b = *(const float4*)(p + 4);
  f[0]=a.x; f[1]=a.y; f[2]=a.z; f[3]=a.w; f[4]=b.x; f[5]=b.y; f[6]=b.z; f[7]=b.w;
}
__device__ __forceinline__ void store8bf(u16* dst, const float* f) {
  u16 t[8];
#pragma unroll
  for (int i = 0; i < 8; ++i) t[i] = f2bf(f[i]);
  *(v8s*)dst = *(const v8s*)t;
}

// ---------- kernel 1: fused zero-flags + convert/pack + mean pass 1 ----------
// blocks 0..5951 convert; 5952..7999 mean pass1; 8000..8015 zero flags
__global__ __launch_bounds__(256) void k_convert_mean(
    const float* __restrict__ Wh, const float* __restrict__ Wm,
    const float* __restrict__ Wih, const float* __restrict__ Whh,
    const float* __restrict__ Wfc, const float* __restrict__ label,
    const float* __restrict__ image,
    u16* __restrict__ wcomb, u16* __restrict__ whhb, u16* __restrict__ wfcb,
    u16* __restrict__ wlabb, u16* __restrict__ labb,
    float4* __restrict__ pacc, unsigned* __restrict__ ctr) {
  const int bid = blockIdx.x, tid = threadIdx.x;
  if (bid >= 8000) {  // zero h-ready flags (16 blocks x 256 = 4096 u32)
    ctr[(bid - 8000) * 256 + tid] = 0u;
    return;
  }
  if (bid >= 5952) {  // mean pass 1: 2048 blocks = b(256) x oct(8)
    int bi = bid - 5952;
    int b = bi >> 3, oct = bi & 7;
    const float4* src =
        (const float4*)image + (size_t)b * 65536 + (size_t)oct * 32 * 256 + tid;
    float4 s = make_float4(0.f, 0.f, 0.f, 0.f);
#pragma unroll 8
    for (int ss = 0; ss < 32; ++ss) {
      float4 v = src[(size_t)ss * 256];
      s.x += v.x; s.y += v.y; s.z += v.z; s.w += v.w;
    }
    pacc[(size_t)bi * 256 + tid] = s;
    return;
  }
  int64_t u = (int64_t)bid * 256 + tid;
  float f[8];
  if (u < 786432) {  // wcomb, KT=16
    int lu = (int)u;
    int r15 = lu & 15, q = (lu >> 4) & 3, s = (lu >> 6) & 1, tile = lu >> 7;
    int tk = tile & 15, tr = tile >> 4;
    int row = tr * 16 + r15, k = tk * 64 + s * 32 + q * 8;
    if (row < 1024) load8(Wh + (size_t)row * 1024 + k, f);
    else if (row < 2048) load8(Wm + (size_t)(row - 1024) * 1024 + k, f);
    else {
      const float* p = Wih + (size_t)(row - 2048) * 1097 + k;
#pragma unroll
      for (int i = 0; i < 8; ++i) f[i] = p[i];
    }
    store8bf(wcomb + (size_t)lu * 8, f);
  } else if (u < 1310720) {  // whhb, KT=16
    int lu = (int)(u - 786432);
    int r15 = lu & 15, q = (lu >> 4) & 3, s = (lu >> 6) & 1, tile = lu >> 7;
    int tk = tile & 15, tr = tile >> 4;
    int row = tr * 16 + r15, k = tk * 64 + s * 32 + q * 8;
    load8(Whh + (size_t)row * 1024 + k, f);
    store8bf(whhb + (size_t)lu * 8, f);
  } else if (u < 1458176) {  // wfcb, KT=16, rows>=1090 zero
    int lu = (int)(u - 1310720);
    int r15 = lu & 15, q = (lu >> 4) & 3, s = (lu >> 6) & 1, tile = lu >> 7;
    int tk = tile & 15, tr = tile >> 4;
    int row = tr * 16 + r15, k = tk * 64 + s * 32 + q * 8;
    if (row < 1090) load8(Wfc + (size_t)row * 1024 + k, f);
    else {
#pragma unroll
      for (int i = 0; i < 8; ++i) f[i] = 0.f;
    }
    store8bf(wfcb + (size_t)lu * 8, f);
  } else if (u < 1490944) {  // wlabb, KT=1
    int lu = (int)(u - 1458176);
    int r15 = lu & 15, q = (lu >> 4) & 3, s = (lu >> 6) & 1, tile = lu >> 7;
    int row = tile * 16 + r15, k = s * 32 + q * 8;
    const float* p = Wih + (size_t)row * 1097 + 1033 + k;
#pragma unroll
    for (int i = 0; i < 8; ++i) f[i] = p[i];
    store8bf(wlabb + (size_t)lu * 8, f);
  } else {  // labb, KT=1, row=t*256+b
    int lu = (int)(u - 1490944);
    int r15 = lu & 15, q = (lu >> 4) & 3, s = (lu >> 6) & 1, tile = lu >> 7;
    int row = tile * 16 + r15, k = s * 32 + q * 8;
    int t = row >> 8, b = row & 255;
    load8(label + ((size_t)b * 17 + t) * 64 + k, f);
    store8bf(labb + (size_t)lu * 8, f);
  }
}

// ---------- kernel 2: mean pass 2 ----------
__global__ __launch_bounds__(256) void k_mean2(const float4* __restrict__ pacc,
                                               u16* __restrict__ meanbf) {
  int b = blockIdx.x, tid = threadIdx.x;
  float4 s = make_float4(0.f, 0.f, 0.f, 0.f);
#pragma unroll
  for (int q = 0; q < 8; ++q) {
    float4 v = pacc[((size_t)b * 8 + q) * 256 + tid];
    s.x += v.x; s.y += v.y; s.z += v.z; s.w += v.w;
  }
  const float inv = 1.f / 256.f;
  int k = tid * 4;
  ushort4 o;
  o.x = f2bf(s.x * inv); o.y = f2bf(s.y * inv);
  o.z = f2bf(s.z * inv); o.w = f2bf(s.w * inv);
  *(ushort4*)&meanbf[fpoff(b, k, 16)] = o;
}

// ---------- kernel 3: mean @ [Wh|Wm|Wih_E]^T -> h0(FP bf16), m0(f32), base(f32) ----------
__global__ __launch_bounds__(256) void k_gemm_init(
    const u16* __restrict__ meanbf, const u16* __restrict__ wcomb,
    const float* __restrict__ bh, const float* __restrict__ bm,
    const float* __restrict__ bih, const float* __restrict__ bhh,
    const float* __restrict__ vp, const float* __restrict__ Wih,
    u16* __restrict__ hbuf, float* __restrict__ mbuf, float* __restrict__ basebuf) {
  __shared__ alignas(16) u16 lA[4 * 1024];
  __shared__ alignas(16) u16 lB[4 * 1024];
  const int tid = threadIdx.x, lane = tid & 63, wid = tid >> 6;
  const int bm0 = (blockIdx.x & 3) * 64;
  const int bn0 = (blockIdx.x >> 2) * 64;  // grid 4*96
  const int wr = wid >> 1, wc = wid & 1;
  v4f acc[2][2];
#pragma unroll
  for (int i = 0; i < 2; ++i)
#pragma unroll
    for (int j = 0; j < 2; ++j) acc[i][j] = (v4f){0.f, 0.f, 0.f, 0.f};

  for (int kt = 0; kt < 16; ++kt) {
    const u16* asrc = meanbf + ((size_t)((bm0 >> 4) + wid) * 16 + kt) * 1024 + lane * 8;
    gll16(asrc, lA + wid * 1024);
    gll16(asrc + 512, lA + wid * 1024 + 512);
    const u16* bsrc = wcomb + ((size_t)((bn0 >> 4) + wid) * 16 + kt) * 1024 + lane * 8;
    gll16(bsrc, lB + wid * 1024);
    gll16(bsrc + 512, lB + wid * 1024 + 512);
    __syncthreads();
#pragma unroll
    for (int s = 0; s < 2; ++s) {
      v8s a0 = *(const v8s*)&lA[(size_t)(wr * 2) * 1024 + s * 512 + lane * 8];
      v8s a1 = *(const v8s*)&lA[(size_t)(wr * 2 + 1) * 1024 + s * 512 + lane * 8];
      v8s b0 = *(const v8s*)&lB[(size_t)(wc * 2) * 1024 + s * 512 + lane * 8];
      v8s b1 = *(const v8s*)&lB[(size_t)(wc * 2 + 1) * 1024 + s * 512 + lane * 8];
      acc[0][0] = mfma16(a0, b0, acc[0][0]);
      acc[0][1] = mfma16(a0, b1, acc[0][1]);
      acc[1][0] = mfma16(a1, b0, acc[1][0]);
      acc[1][1] = mfma16(a1, b1, acc[1][1]);
    }
    __syncthreads();
  }
#pragma unroll
  for (int fm = 0; fm < 2; ++fm)
#pragma unroll
    for (int fn = 0; fn < 2; ++fn)
#pragma unroll
      for (int rg = 0; rg < 4; ++rg) {
        int row = bm0 + wr * 32 + fm * 16 + ((lane >> 4) << 2) + rg;  // b
        int col = bn0 + wc * 32 + fn * 16 + (lane & 15);              // packed n
        float v = acc[fm][fn][rg];
        if (col < 1024) {
          hbuf[fpoff(row, col, 16)] = f2bf(tanhf_fast(v + bh[col]));
        } else if (col < 2048) {
          int nn = col - 1024;
          mbuf[(size_t)row * 1024 + nn] = tanhf_fast(v + bm[nn]);
        } else {
          int j = col - 2048;
          float sv = v + bih[j] + bhh[j];
#pragma unroll
          for (int q = 0; q < 8; ++q)
            sv += vp[row * 8 + q] * Wih[(size_t)j * 1097 + 1024 + q];
          basebuf[(size_t)row * 4096 + j] = sv;
        }
      }
}

// ---------- kernel 5: persistent 16-step LSTM, weight-stationary in VGPRs ----------
// grid 256, wave w = gate w. Whh slice + Wlab slice + base/W_begin in regs;
// all 16 label tiles staged once in LDS. Split-dependency schedule: MFMA half0
// (kt 0-7) depends only on producers n0idx 0-15; half1 on 16-31. Wave0 polls
// half0 flags, all stage half0 + bias-GEMM while wave0 polls half1 flags ->
// half1 producers get ~1.5us slack (absorbs producer skew, the measured cost).
__global__ __launch_bounds__(256, 1) void k_steps(
    const u16* __restrict__ whhb, const u16* __restrict__ wlabb,
    const u16* __restrict__ labb, const float* __restrict__ basebuf,
    const float* __restrict__ Wih, const float* __restrict__ mbuf,
    u16* __restrict__ hbuf, unsigned* __restrict__ ctr) {
  __shared__ alignas(16) u16 lA[64 * 512];      // 64 KB: 64 FP chunks of h[t]
  __shared__ alignas(16) u16 lLab[64 * 512];    // 64 KB: lab tiles, all 16 steps
  __shared__ alignas(16) float lact[4][32 * 33];
  const int tid = threadIdx.x, lane = tid & 63, wid = tid >> 6;
  const int blk = blockIdx.x;
  const int n0idx = (blk & 7) * 4 + (blk >> 6);  // 0..31
  const int n0 = n0idx * 32;
  const int grp = (blk >> 3) & 7;                // b0-group: share h rows
  const int b0 = grp * 32;
  const int atr = b0 >> 4;

  // stage ALL label tiles: chunk c=t*4+i*2+s -> labb tile (t*16+atr+i), chunk s
#pragma unroll
  for (int j = 0; j < 16; ++j) {
    const int c = wid * 16 + j;
    const int t = c >> 2, i = (c >> 1) & 1, s = c & 1;
    gll16(labb + (size_t)(t * 16 + atr + i) * 1024 + s * 512 + lane * 8,
          lLab + c * 512);
  }

  // B preload: gate wid, n-tiles tr0,tr0+1, all 16 k-tiles -> 64 v8s (regs/AGPRs)
  const int tr0 = wid * 64 + (n0 >> 4);
  v8s breg[16][2][2];
#pragma unroll
  for (int kt = 0; kt < 16; ++kt)
#pragma unroll
    for (int s = 0; s < 2; ++s)
#pragma unroll
      for (int j = 0; j < 2; ++j)
        breg[kt][s][j] =
            *(const v8s*)&whhb[((size_t)(tr0 + j) * 16 + kt) * 1024 + s * 512 + lane * 8];
  // Wlab slice: same tiles, KT=1
  v8s wlreg[2][2];
#pragma unroll
  for (int s = 0; s < 2; ++s)
#pragma unroll
    for (int j = 0; j < 2; ++j)
      wlreg[s][j] = *(const v8s*)&wlabb[(size_t)(tr0 + j) * 1024 + s * 512 + lane * 8];

  // per-thread state: thread -> (b0+rowm, n0+nql..+3)
  const int rowm = tid >> 3;
  const int nql = (tid & 7) * 4;
  const int b = b0 + rowm;
  const int n = n0 + nql;
  float4 mreg = *(const float4*)&mbuf[(size_t)b * 1024 + n];
  float4 bse[4], wbv[4];
#pragma unroll
  for (int g = 0; g < 4; ++g) {
    bse[g] = *(const float4*)&basebuf[(size_t)b * 4096 + g * 1024 + n];
#pragma unroll
    for (int q = 0; q < 4; ++q)
      ((float*)&wbv[g])[q] = Wih[(size_t)(g * 1024 + n + q) * 1097 + 1032];
  }
  __syncthreads();  // drains lLab gll16s + all preloads

  for (int t = 0; t < 16; ++t) {
    // wait for half0 producers (n0idx 0..15) of h[t]; wave-0-only poll
    if (t > 0) {
      if (wid == 0) {
        const unsigned* f = &ctr[((t - 1) * 8 + grp) * 32];
        for (int it = 0; it < (1 << 18); ++it) {
          unsigned v = __hip_atomic_load(&f[lane & 15], __ATOMIC_RELAXED,
                                         __HIP_MEMORY_SCOPE_AGENT);
          if (__ballot((lane < 16) && v == 0u) == 0ull) break;
          __builtin_amdgcn_s_sleep(1);
        }
      }
      __builtin_amdgcn_s_barrier();   // raw: no drain; half0 of h[t] is ready
      __builtin_amdgcn_sched_barrier(0);
    }
    const u16* hsrc = hbuf + (size_t)t * 262144;
    __builtin_amdgcn_sched_barrier(0);
    // h half0: per-wave chunks hc=wid*8+j -> (i=hc>>4, kt=(hc>>1)&7, s=hc&1)
#pragma unroll
    for (int j = 0; j < 8; ++j) {
      const int hc = wid * 8 + j;
      const int i = hc >> 4, kt = (hc >> 1) & 7, s = hc & 1;
      gll16(hsrc + ((size_t)(atr + i) * 16 + kt) * 1024 + s * 512 + lane * 8,
            lA + (i * 32 + kt * 2 + s) * 512);
    }
    __builtin_amdgcn_sched_barrier(0);

    // wave0: poll half1 producers (n0idx 16..31) — overlaps half0 flight;
    // waves 1-3: run the bias GEMM meanwhile (order per-wave is free)
    v4f acc[2][2];
#pragma unroll
    for (int i = 0; i < 2; ++i)
#pragma unroll
      for (int j = 0; j < 2; ++j) acc[i][j] = (v4f){0.f, 0.f, 0.f, 0.f};

    if (t > 0 && wid == 0) {
      const unsigned* f = &ctr[((t - 1) * 8 + grp) * 32 + 16];
      for (int it = 0; it < (1 << 18); ++it) {
        unsigned v = __hip_atomic_load(&f[lane & 15], __ATOMIC_RELAXED,
                                       __HIP_MEMORY_SCOPE_AGENT);
        if (__ballot((lane < 16) && v == 0u) == 0ull) break;
        __builtin_amdgcn_s_sleep(1);
      }
    }
    // bias GEMM: acc = lab[t] @ Wlab^T (LDS+reg only)
#pragma unroll
    for (int s = 0; s < 2; ++s) {
      v8s aL0 = *(const v8s*)&lLab[(size_t)(t * 4 + 0 * 2 + s) * 512 + lane * 8];
      v8s aL1 = *(const v8s*)&lLab[(size_t)(t * 4 + 1 * 2 + s) * 512 + lane * 8];
      acc[0][0] = mfma16(aL0, wlreg[s][0], acc[0][0]);
      acc[0][1] = mfma16(aL0, wlreg[s][1], acc[0][1]);
      acc[1][0] = mfma16(aL1, wlreg[s][0], acc[1][0]);
      acc[1][1] = mfma16(aL1, wlreg[s][1], acc[1][1]);
    }
    __builtin_amdgcn_sched_barrier(0);
    __builtin_amdgcn_s_barrier();     // raw: half1 of h[t] is ready
    __builtin_amdgcn_sched_barrier(0);

    // h half1: kt+8 (producers 16..31 now known done)
#pragma unroll
    for (int j = 0; j < 8; ++j) {
      const int hc = wid * 8 + j;
      const int i = hc >> 4, kt = ((hc >> 1) & 7) + 8, s = hc & 1;
      gll16(hsrc + ((size_t)(atr + i) * 16 + kt) * 1024 + s * 512 + lane * 8,
            lA + (i * 32 + kt * 2 + s) * 512);
    }
    __builtin_amdgcn_sched_barrier(0);
    asm volatile("s_waitcnt vmcnt(8)" ::: "memory");   // half0 landed
    // (wave0 over-drained by its polls: safe/conservative)
    __builtin_amdgcn_sched_barrier(0);
    __builtin_amdgcn_s_barrier();
    __builtin_amdgcn_sched_barrier(0);
#pragma unroll
    for (int kt = 0; kt < 8; ++kt)
#pragma unroll
      for (int s = 0; s < 2; ++s) {
        v8s a0 = *(const v8s*)&lA[(size_t)((0 * 16 + kt) * 2 + s) * 512 + lane * 8];
        v8s a1 = *(const v8s*)&lA[(size_t)((1 * 16 + kt) * 2 + s) * 512 + lane * 8];
        acc[0][0] = mfma16(a0, breg[kt][s][0], acc[0][0]);
        acc[0][1] = mfma16(a0, breg[kt][s][1], acc[0][1]);
        acc[1][0] = mfma16(a1, breg[kt][s][0], acc[1][0]);
        acc[1][1] = mfma16(a1, breg[kt][s][1], acc[1][1]);
      }

    __builtin_amdgcn_sched_barrier(0);
    asm volatile("s_waitcnt vmcnt(0)" ::: "memory");   // half1 landed
    __builtin_amdgcn_sched_barrier(0);
    __builtin_amdgcn_s_barrier();
    __builtin_amdgcn_sched_barrier(0);
#pragma unroll
    for (int kt = 8; kt < 16; ++kt)
#pragma unroll
      for (int s = 0; s < 2; ++s) {
        v8s a0 = *(const v8s*)&lA[(size_t)((0 * 16 + kt) * 2 + s) * 512 + lane * 8];
        v8s a1 = *(const v8s*)&lA[(size_t)((1 * 16 + kt) * 2 + s) * 512 + lane * 8];
        acc[0][0] = mfma16(a0, breg[kt][s][0], acc[0][0]);
        acc[0][1] = mfma16(a0, breg[kt][s][1], acc[0][1]);
        acc[1][0] = mfma16(a1, breg[kt][s][0], acc[1][0]);
        acc[1][1] = mfma16(a1, breg[kt][s][1], acc[1][1]);
      }

#pragma unroll
    for (int fm = 0; fm < 2; ++fm)
#pragma unroll
      for (int fn = 0; fn < 2; ++fn)
#pragma unroll
        for (int rg = 0; rg < 4; ++rg) {
          int rr = fm * 16 + ((lane >> 4) << 2) + rg;
          int cc = fn * 16 + (lane & 15);
          lact[wid][rr * 33 + cc] = acc[fm][fn][rg];
        }
    __syncthreads();

    // activations: gates = lact + base (+ W_begin at t=0)
    const float w0 = (t == 0) ? 1.f : 0.f;
    float m2a[4];
    u16 h2a[4];
#pragma unroll
    for (int q = 0; q < 4; ++q) {
      float gi = lact[0][rowm * 33 + nql + q] + ((const float*)&bse[0])[q] + w0 * ((const float*)&wbv[0])[q];
      float gf = lact[1][rowm * 33 + nql + q] + ((const float*)&bse[1])[q] + w0 * ((const float*)&wbv[1])[q];
      float gg = lact[2][rowm * 33 + nql + q] + ((const float*)&bse[2])[q] + w0 * ((const float*)&wbv[2])[q];
      float go = lact[3][rowm * 33 + nql + q] + ((const float*)&bse[3])[q] + w0 * ((const float*)&wbv[3])[q];
      float mov = ((const float*)&mreg)[q];
      float m2 = sigf(gf) * mov + sigf(gi) * tanhf_fast(gg);
      float h2 = sigf(go) * tanhf_fast(m2);
      m2a[q] = m2;
      h2a[q] = f2bf(h2);
    }
    mreg = make_float4(m2a[0], m2a[1], m2a[2], m2a[3]);
    ushort4 ho;
    ho.x = h2a[0]; ho.y = h2a[1]; ho.z = h2a[2]; ho.w = h2a[3];
    // coherent h-store: 8B relaxed agent atomic store (8B-aligned FP address)
    unsigned long long hv;
    __builtin_memcpy(&hv, &ho, 8);
    __hip_atomic_store(
        reinterpret_cast<unsigned long long*>(
            &hbuf[(size_t)(t + 1) * 262144 + fpoff(b, n, 16)]),
        hv, __ATOMIC_RELAXED, __HIP_MEMORY_SCOPE_AGENT);

    if (t < 15) {
      __syncthreads();  // drains vmcnt: all 4 waves' h-stores acked
      if (tid == 0)     // per-producer flag: plain store, no RMW
        __hip_atomic_store(&ctr[(t * 8 + grp) * 32 + n0idx], 1u,
                           __ATOMIC_RELAXED, __HIP_MEMORY_SCOPE_AGENT);
    }
  }
}

// ---------- kernel 6: batched FC + epilogue + mask ----------
__global__ __launch_bounds__(256) void k_fc(
    const u16* __restrict__ hall, const u16* __restrict__ wfcb,
    const float* __restrict__ bfc, const int* __restrict__ length,
    float* __restrict__ out) {
  __shared__ alignas(16) u16 lA[4 * 1024];
  __shared__ alignas(16) u16 lB[4 * 1024];
  const int tid = threadIdx.x, lane = tid & 63, wid = tid >> 6;
  const int bm0 = (int)(blockIdx.x % 64) * 64;
  const int bn0 = (int)(blockIdx.x / 64) * 64;  // grid 64*18
  const int wr = wid >> 1, wc = wid & 1;
  v4f acc[2][2];
#pragma unroll
  for (int i = 0; i < 2; ++i)
#pragma unroll
    for (int j = 0; j < 2; ++j) acc[i][j] = (v4f){0.f, 0.f, 0.f, 0.f};

  for (int kt = 0; kt < 16; ++kt) {
    const u16* asrc = hall + ((size_t)((bm0 >> 4) + wid) * 16 + kt) * 1024 + lane * 8;
    gll16(asrc, lA + wid * 1024);
    gll16(asrc + 512, lA + wid * 1024 + 512);
    const u16* bsrc = wfcb + ((size_t)((bn0 >> 4) + wid) * 16 + kt) * 1024 + lane * 8;
    gll16(bsrc, lB + wid * 1024);
    gll16(bsrc + 512, lB + wid * 1024 + 512);
    __syncthreads();
#pragma unroll
    for (int s = 0; s < 2; ++s) {
      v8s a0 = *(const v8s*)&lA[(size_t)(wr * 2) * 1024 + s * 512 + lane * 8];
      v8s a1 = *(const v8s*)&lA[(size_t)(wr * 2 + 1) * 1024 + s * 512 + lane * 8];
      v8s b0 = *(const v8s*)&lB[(size_t)(wc * 2) * 1024 + s * 512 + lane * 8];
      v8s b1 = *(const v8s*)&lB[(size_t)(wc * 2 + 1) * 1024 + s * 512 + lane * 8];
      acc[0][0] = mfma16(a0, b0, acc[0][0]);
      acc[0][1] = mfma16(a0, b1, acc[0][1]);
      acc[1][0] = mfma16(a1, b0, acc[1][0]);
      acc[1][1] = mfma16(a1, b1, acc[1][1]);
    }
    __syncthreads();
  }
#pragma unroll
  for (int fm = 0; fm < 2; ++fm)
#pragma unroll
    for (int fn = 0; fn < 2; ++fn)
#pragma unroll
      for (int rg = 0; rg < 4; ++rg) {
        int r = bm0 + wr * 32 + fm * 16 + ((lane >> 4) << 2) + rg;
        int j = bn0 + wc * 32 + fn * 16 + (lane & 15);
        if (j < 64 || j >= 1090) continue;
        int t = r >> 8, b = r & 255;
        float v = acc[fm][fn][rg] + bfc[j];
        int c;
        if (j < 1088) { c = j - 64; v = fmaxf(v, 0.f); }
        else if (j == 1088) { c = 1024; v = 1.f / (1.f + expf(-v)); }
        else { c = 1025; v = expf(v); }
        if (t >= length[b] - 1) v = 0.f;
        out[((size_t)t * 256 + b) * 1026 + c] = v;
      }
}

extern "C" void kernel_launch(void* const* d_in, const int* in_sizes, int n_in,
                              void* d_out, int out_size, void* d_ws, size_t ws_size,
                              hipStream_t stream) {
  (void)in_sizes; (void)n_in; (void)out_size; (void)ws_size;
  const float* image  = (const float*)d_in[0];
  const float* vp     = (const float*)d_in[1];
  const float* label  = (const float*)d_in[2];
  const int*   length = (const int*)d_in[3];
  const float* Wh  = (const float*)d_in[4];
  const float* bh  = (const float*)d_in[5];
  const float* Wm  = (const float*)d_in[6];
  const float* bm  = (const float*)d_in[7];
  const float* Wih = (const float*)d_in[8];
  const float* Whh = (const float*)d_in[9];
  const float* bih = (const float*)d_in[10];
  const float* bhh = (const float*)d_in[11];
  const float* Wfc = (const float*)d_in[12];
  const float* bfc = (const float*)d_in[13];
  float* out = (float*)d_out;
  char* ws = (char*)d_ws;

  size_t off = 0;
  u16* wcomb  = (u16*)(ws + off); off += (size_t)6144 * 1024 * 2;
  u16* whhb   = (u16*)(ws + off); off += (size_t)4096 * 1024 * 2;
  u16* wfcb   = (u16*)(ws + off); off += (size_t)1152 * 1024 * 2;
  u16* wlabb  = (u16*)(ws + off); off += (size_t)4096 * 64 * 2;
  u16* labb   = (u16*)(ws + off); off += (size_t)4096 * 64 * 2;
  u16* meanbf = (u16*)(ws + off); off += (size_t)256 * 1024 * 2;
  u16* hbuf   = (u16*)(ws + off); off += (size_t)17 * 256 * 1024 * 2;
  float* mbuf    = (float*)(ws + off); off += (size_t)256 * 1024 * 4;
  float* basebuf = (float*)(ws + off); off += (size_t)256 * 4096 * 4;
  unsigned* ctr = (unsigned*)(ws + off); off += 4096 * 4;
  float4* pacc = (float4*)(ws + off); off += (size_t)2048 * 256 * 16;

  k_convert_mean<<<8016, 256, 0, stream>>>(Wh, Wm, Wih, Whh, Wfc, label, image,
                                           wcomb, whhb, wfcb, wlabb, labb, pacc, ctr);
  k_mean2<<<256, 256, 0, stream>>>(pacc, meanbf);
  k_gemm_init<<<384, 256, 0, stream>>>(meanbf, wcomb, bh, bm, bih, bhh, vp, Wih,
                                       hbuf, mbuf, basebuf);
  k_steps<<<256, 256, 0, stream>>>(whhb, wlabb, labb, basebuf, Wih, mbuf, hbuf, ctr);
  k_fc<<<1152, 256, 0, stream>>>(hbuf + (size_t)256 * 1024, wfcb, bfc, length, out);
}

// Round 13
// 192.799 us; speedup vs baseline: 1.0512x; 1.0185x over previous
//
#include <hip/hip_runtime.h>
#include <stdint.h>

typedef unsigned short u16;
typedef __attribute__((ext_vector_type(8))) short v8s;
typedef __attribute__((ext_vector_type(4))) float v4f;

// ---------- helpers ----------
__device__ __forceinline__ u16 f2bf(float f) {
  uint32_t x = __float_as_uint(f);
  return (u16)((x + 0x7fffu + ((x >> 16) & 1u)) >> 16);
}
__device__ __forceinline__ float bf2f(u16 u) {
  return __uint_as_float(((uint32_t)u) << 16);
}
__device__ __forceinline__ float sigf(float x) { return 1.f / (1.f + __expf(-x)); }
// fast tanh: |err| ~1e-6, far below bf16 quantization
__device__ __forceinline__ float tanhf_fast(float x) {
  float e = __expf(-2.f * fabsf(x));
  float r = (1.f - e) / (1.f + e);
  return copysignf(r, x);
}

__device__ __forceinline__ v4f mfma16(v8s a, v8s b, v4f c) {
  return __builtin_amdgcn_mfma_f32_16x16x32_bf16(a, b, c, 0, 0, 0);
}

// async global->LDS, 16B/lane; LDS dest wave-uniform (HW adds lane*16)
__device__ __forceinline__ void gll16(const u16* src, u16* ldsdst) {
  __builtin_amdgcn_global_load_lds(
      reinterpret_cast<__attribute__((address_space(1))) uint32_t*>(
          reinterpret_cast<uintptr_t>(src)),
      reinterpret_cast<__attribute__((address_space(3))) uint32_t*>(
          reinterpret_cast<uintptr_t>(ldsdst)),
      16, 0, 0);
}

// Fragment-packed (FP) layout for bf16 matrix M[R][K] (R%16==0, K%64==0, KT=K/64):
// chunk s of tile (tr,tk), lane l (= q*16+r) holds M[tr*16+r][tk*64+s*32+q*8 ..+7].
__device__ __forceinline__ size_t fpoff(int row, int k, int KT) {
  return ((size_t)(((row >> 4) * KT + (k >> 6)) * 2 + ((k >> 5) & 1)) * 64 +
          ((k >> 3) & 3) * 16 + (row & 15)) * 8 + (k & 7);
}

__device__ __forceinline__ void load8(const float* p, float* f) {
  float4 a = *(const float4*)p;
  float4 b = *(const float4*)(p + 4);
  f[0]=a.x; f[1]=a.y; f[2]=a.z; f[3]=a.w; f[4]=b.x; f[5]=b.y; f[6]=b.z; f[7]=b.w;
}
__device__ __forceinline__ void store8bf(u16* dst, const float* f) {
  u16 t[8];
#pragma unroll
  for (int i = 0; i < 8; ++i) t[i] = f2bf(f[i]);
  *(v8s*)dst = *(const v8s*)t;
}

// ---------- kernel 1: fused zero-flags + convert/pack + mean pass 1 ----------
// blocks 0..5951 convert; 5952..7999 mean pass1; 8000..8015 zero flags
__global__ __launch_bounds__(256) void k_convert_mean(
    const float* __restrict__ Wh, const float* __restrict__ Wm,
    const float* __restrict__ Wih, const float* __restrict__ Whh,
    const float* __restrict__ Wfc, const float* __restrict__ label,
    const float* __restrict__ image,
    u16* __restrict__ wcomb, u16* __restrict__ whhb, u16* __restrict__ wfcb,
    u16* __restrict__ wlabb, u16* __restrict__ labb,
    float4* __restrict__ pacc, unsigned* __restrict__ ctr) {
  const int bid = blockIdx.x, tid = threadIdx.x;
  if (bid >= 8000) {  // zero h-ready flags (16 blocks x 256 = 4096 u32)
    ctr[(bid - 8000) * 256 + tid] = 0u;
    return;
  }
  if (bid >= 5952) {  // mean pass 1: 2048 blocks = b(256) x oct(8)
    int bi = bid - 5952;
    int b = bi >> 3, oct = bi & 7;
    const float4* src =
        (const float4*)image + (size_t)b * 65536 + (size_t)oct * 32 * 256 + tid;
    float4 s = make_float4(0.f, 0.f, 0.f, 0.f);
#pragma unroll 8
    for (int ss = 0; ss < 32; ++ss) {
      float4 v = src[(size_t)ss * 256];
      s.x += v.x; s.y += v.y; s.z += v.z; s.w += v.w;
    }
    pacc[(size_t)bi * 256 + tid] = s;
    return;
  }
  int64_t u = (int64_t)bid * 256 + tid;
  float f[8];
  if (u < 786432) {  // wcomb, KT=16
    int lu = (int)u;
    int r15 = lu & 15, q = (lu >> 4) & 3, s = (lu >> 6) & 1, tile = lu >> 7;
    int tk = tile & 15, tr = tile >> 4;
    int row = tr * 16 + r15, k = tk * 64 + s * 32 + q * 8;
    if (row < 1024) load8(Wh + (size_t)row * 1024 + k, f);
    else if (row < 2048) load8(Wm + (size_t)(row - 1024) * 1024 + k, f);
    else {
      const float* p = Wih + (size_t)(row - 2048) * 1097 + k;
#pragma unroll
      for (int i = 0; i < 8; ++i) f[i] = p[i];
    }
    store8bf(wcomb + (size_t)lu * 8, f);
  } else if (u < 1310720) {  // whhb, KT=16
    int lu = (int)(u - 786432);
    int r15 = lu & 15, q = (lu >> 4) & 3, s = (lu >> 6) & 1, tile = lu >> 7;
    int tk = tile & 15, tr = tile >> 4;
    int row = tr * 16 + r15, k = tk * 64 + s * 32 + q * 8;
    load8(Whh + (size_t)row * 1024 + k, f);
    store8bf(whhb + (size_t)lu * 8, f);
  } else if (u < 1458176) {  // wfcb, KT=16, rows>=1090 zero
    int lu = (int)(u - 1310720);
    int r15 = lu & 15, q = (lu >> 4) & 3, s = (lu >> 6) & 1, tile = lu >> 7;
    int tk = tile & 15, tr = tile >> 4;
    int row = tr * 16 + r15, k = tk * 64 + s * 32 + q * 8;
    if (row < 1090) load8(Wfc + (size_t)row * 1024 + k, f);
    else {
#pragma unroll
      for (int i = 0; i < 8; ++i) f[i] = 0.f;
    }
    store8bf(wfcb + (size_t)lu * 8, f);
  } else if (u < 1490944) {  // wlabb, KT=1
    int lu = (int)(u - 1458176);
    int r15 = lu & 15, q = (lu >> 4) & 3, s = (lu >> 6) & 1, tile = lu >> 7;
    int row = tile * 16 + r15, k = s * 32 + q * 8;
    const float* p = Wih + (size_t)row * 1097 + 1033 + k;
#pragma unroll
    for (int i = 0; i < 8; ++i) f[i] = p[i];
    store8bf(wlabb + (size_t)lu * 8, f);
  } else {  // labb, KT=1, row=t*256+b
    int lu = (int)(u - 1490944);
    int r15 = lu & 15, q = (lu >> 4) & 3, s = (lu >> 6) & 1, tile = lu >> 7;
    int row = tile * 16 + r15, k = s * 32 + q * 8;
    int t = row >> 8, b = row & 255;
    load8(label + ((size_t)b * 17 + t) * 64 + k, f);
    store8bf(labb + (size_t)lu * 8, f);
  }
}

// ---------- kernel 2: mean pass 2 ----------
__global__ __launch_bounds__(256) void k_mean2(const float4* __restrict__ pacc,
                                               u16* __restrict__ meanbf) {
  int b = blockIdx.x, tid = threadIdx.x;
  float4 s = make_float4(0.f, 0.f, 0.f, 0.f);
#pragma unroll
  for (int q = 0; q < 8; ++q) {
    float4 v = pacc[((size_t)b * 8 + q) * 256 + tid];
    s.x += v.x; s.y += v.y; s.z += v.z; s.w += v.w;
  }
  const float inv = 1.f / 256.f;
  int k = tid * 4;
  ushort4 o;
  o.x = f2bf(s.x * inv); o.y = f2bf(s.y * inv);
  o.z = f2bf(s.z * inv); o.w = f2bf(s.w * inv);
  *(ushort4*)&meanbf[fpoff(b, k, 16)] = o;
}

// ---------- kernel 3: mean @ [Wh|Wm|Wih_E]^T -> h0(FP bf16), m0(f32), base(f32) ----------
__global__ __launch_bounds__(256) void k_gemm_init(
    const u16* __restrict__ meanbf, const u16* __restrict__ wcomb,
    const float* __restrict__ bh, const float* __restrict__ bm,
    const float* __restrict__ bih, const float* __restrict__ bhh,
    const float* __restrict__ vp, const float* __restrict__ Wih,
    u16* __restrict__ hbuf, float* __restrict__ mbuf, float* __restrict__ basebuf) {
  __shared__ alignas(16) u16 lA[4 * 1024];
  __shared__ alignas(16) u16 lB[4 * 1024];
  const int tid = threadIdx.x, lane = tid & 63, wid = tid >> 6;
  const int bm0 = (blockIdx.x & 3) * 64;
  const int bn0 = (blockIdx.x >> 2) * 64;  // grid 4*96
  const int wr = wid >> 1, wc = wid & 1;
  v4f acc[2][2];
#pragma unroll
  for (int i = 0; i < 2; ++i)
#pragma unroll
    for (int j = 0; j < 2; ++j) acc[i][j] = (v4f){0.f, 0.f, 0.f, 0.f};

  for (int kt = 0; kt < 16; ++kt) {
    const u16* asrc = meanbf + ((size_t)((bm0 >> 4) + wid) * 16 + kt) * 1024 + lane * 8;
    gll16(asrc, lA + wid * 1024);
    gll16(asrc + 512, lA + wid * 1024 + 512);
    const u16* bsrc = wcomb + ((size_t)((bn0 >> 4) + wid) * 16 + kt) * 1024 + lane * 8;
    gll16(bsrc, lB + wid * 1024);
    gll16(bsrc + 512, lB + wid * 1024 + 512);
    __syncthreads();
#pragma unroll
    for (int s = 0; s < 2; ++s) {
      v8s a0 = *(const v8s*)&lA[(size_t)(wr * 2) * 1024 + s * 512 + lane * 8];
      v8s a1 = *(const v8s*)&lA[(size_t)(wr * 2 + 1) * 1024 + s * 512 + lane * 8];
      v8s b0 = *(const v8s*)&lB[(size_t)(wc * 2) * 1024 + s * 512 + lane * 8];
      v8s b1 = *(const v8s*)&lB[(size_t)(wc * 2 + 1) * 1024 + s * 512 + lane * 8];
      acc[0][0] = mfma16(a0, b0, acc[0][0]);
      acc[0][1] = mfma16(a0, b1, acc[0][1]);
      acc[1][0] = mfma16(a1, b0, acc[1][0]);
      acc[1][1] = mfma16(a1, b1, acc[1][1]);
    }
    __syncthreads();
  }
#pragma unroll
  for (int fm = 0; fm < 2; ++fm)
#pragma unroll
    for (int fn = 0; fn < 2; ++fn)
#pragma unroll
      for (int rg = 0; rg < 4; ++rg) {
        int row = bm0 + wr * 32 + fm * 16 + ((lane >> 4) << 2) + rg;  // b
        int col = bn0 + wc * 32 + fn * 16 + (lane & 15);              // packed n
        float v = acc[fm][fn][rg];
        if (col < 1024) {
          hbuf[fpoff(row, col, 16)] = f2bf(tanhf_fast(v + bh[col]));
        } else if (col < 2048) {
          int nn = col - 1024;
          mbuf[(size_t)row * 1024 + nn] = tanhf_fast(v + bm[nn]);
        } else {
          int j = col - 2048;
          float sv = v + bih[j] + bhh[j];
#pragma unroll
          for (int q = 0; q < 8; ++q)
            sv += vp[row * 8 + q] * Wih[(size_t)j * 1097 + 1024 + q];
          basebuf[(size_t)row * 4096 + j] = sv;
        }
      }
}

// ---------- kernel 5: persistent 16-step LSTM, weight-stationary in VGPRs ----------
// grid 256, wave w = gate w. Whh slice + Wlab slice + base/W_begin in regs;
// all 16 label tiles staged once in LDS. Per step: bias via 8 MFMAs (acc init),
// h-stage pipelined with counted vmcnt; coherent h-store + flag handoff.
// Poll discipline: ONLY wave 0 polls the flag line; waves 1-3 wait at barrier.
__global__ __launch_bounds__(256, 1) void k_steps(
    const u16* __restrict__ whhb, const u16* __restrict__ wlabb,
    const u16* __restrict__ labb, const float* __restrict__ basebuf,
    const float* __restrict__ Wih, const float* __restrict__ mbuf,
    u16* __restrict__ hbuf, unsigned* __restrict__ ctr) {
  __shared__ alignas(16) u16 lA[64 * 512];      // 64 KB: 64 FP chunks of h[t]
  __shared__ alignas(16) u16 lLab[64 * 512];    // 64 KB: lab tiles, all 16 steps
  __shared__ alignas(16) float lact[4][32 * 33];
  const int tid = threadIdx.x, lane = tid & 63, wid = tid >> 6;
  const int blk = blockIdx.x;
  const int n0idx = (blk & 7) * 4 + (blk >> 6);  // 0..31
  const int n0 = n0idx * 32;
  const int grp = (blk >> 3) & 7;                // b0-group: share h rows
  const int b0 = grp * 32;
  const int atr = b0 >> 4;

  // stage ALL label tiles: chunk c=t*4+i*2+s -> labb tile (t*16+atr+i), chunk s
#pragma unroll
  for (int j = 0; j < 16; ++j) {
    const int c = wid * 16 + j;
    const int t = c >> 2, i = (c >> 1) & 1, s = c & 1;
    gll16(labb + (size_t)(t * 16 + atr + i) * 1024 + s * 512 + lane * 8,
          lLab + c * 512);
  }

  // B preload: gate wid, n-tiles tr0,tr0+1, all 16 k-tiles -> 64 v8s (regs/AGPRs)
  const int tr0 = wid * 64 + (n0 >> 4);
  v8s breg[16][2][2];
#pragma unroll
  for (int kt = 0; kt < 16; ++kt)
#pragma unroll
    for (int s = 0; s < 2; ++s)
#pragma unroll
      for (int j = 0; j < 2; ++j)
        breg[kt][s][j] =
            *(const v8s*)&whhb[((size_t)(tr0 + j) * 16 + kt) * 1024 + s * 512 + lane * 8];
  // Wlab slice: same tiles, KT=1
  v8s wlreg[2][2];
#pragma unroll
  for (int s = 0; s < 2; ++s)
#pragma unroll
    for (int j = 0; j < 2; ++j)
      wlreg[s][j] = *(const v8s*)&wlabb[(size_t)(tr0 + j) * 1024 + s * 512 + lane * 8];

  // per-thread state: thread -> (b0+rowm, n0+nql..+3)
  const int rowm = tid >> 3;
  const int nql = (tid & 7) * 4;
  const int b = b0 + rowm;
  const int n = n0 + nql;
  float4 mreg = *(const float4*)&mbuf[(size_t)b * 1024 + n];
  float4 bse[4], wbv[4];
#pragma unroll
  for (int g = 0; g < 4; ++g) {
    bse[g] = *(const float4*)&basebuf[(size_t)b * 4096 + g * 1024 + n];
#pragma unroll
    for (int q = 0; q < 4; ++q)
      ((float*)&wbv[g])[q] = Wih[(size_t)(g * 1024 + n + q) * 1097 + 1032];
  }
  __syncthreads();  // drains lLab gll16s + all preloads

  for (int t = 0; t < 16; ++t) {
    // wait for h[t] producers (t=0 ready via kernel boundary); wave-0-only poll
    if (t > 0) {
      if (wid == 0) {
        const unsigned* f = &ctr[((t - 1) * 8 + grp) * 32];
        for (int it = 0; it < (1 << 18); ++it) {
          unsigned v = __hip_atomic_load(&f[lane & 31], __ATOMIC_RELAXED,
                                         __HIP_MEMORY_SCOPE_AGENT);
          if (__ballot(v == 0u) == 0ull) break;
          __builtin_amdgcn_s_sleep(2);
        }
      }
      __syncthreads();
    }
    const u16* hsrc = hbuf + (size_t)t * 262144;
    __builtin_amdgcn_sched_barrier(0);
    // h half0: per-wave chunks hc=wid*8+j -> (i=hc>>4, kt=(hc>>1)&7, s=hc&1)
#pragma unroll
    for (int j = 0; j < 8; ++j) {
      const int hc = wid * 8 + j;
      const int i = hc >> 4, kt = (hc >> 1) & 7, s = hc & 1;
      gll16(hsrc + ((size_t)(atr + i) * 16 + kt) * 1024 + s * 512 + lane * 8,
            lA + (i * 32 + kt * 2 + s) * 512);
    }
    __builtin_amdgcn_sched_barrier(0);
    // h half1: kt+8
#pragma unroll
    for (int j = 0; j < 8; ++j) {
      const int hc = wid * 8 + j;
      const int i = hc >> 4, kt = ((hc >> 1) & 7) + 8, s = hc & 1;
      gll16(hsrc + ((size_t)(atr + i) * 16 + kt) * 1024 + s * 512 + lane * 8,
            lA + (i * 32 + kt * 2 + s) * 512);
    }
    __builtin_amdgcn_sched_barrier(0);

    // bias GEMM: acc = lab[t] @ Wlab^T (LDS+reg only; hides stage latency)
    v4f acc[2][2];
#pragma unroll
    for (int i = 0; i < 2; ++i)
#pragma unroll
      for (int j = 0; j < 2; ++j) acc[i][j] = (v4f){0.f, 0.f, 0.f, 0.f};
#pragma unroll
    for (int s = 0; s < 2; ++s) {
      v8s aL0 = *(const v8s*)&lLab[(size_t)(t * 4 + 0 * 2 + s) * 512 + lane * 8];
      v8s aL1 = *(const v8s*)&lLab[(size_t)(t * 4 + 1 * 2 + s) * 512 + lane * 8];
      acc[0][0] = mfma16(aL0, wlreg[s][0], acc[0][0]);
      acc[0][1] = mfma16(aL0, wlreg[s][1], acc[0][1]);
      acc[1][0] = mfma16(aL1, wlreg[s][0], acc[1][0]);
      acc[1][1] = mfma16(aL1, wlreg[s][1], acc[1][1]);
    }

    __builtin_amdgcn_sched_barrier(0);
    asm volatile("s_waitcnt vmcnt(8)" ::: "memory");   // h half0 landed
    __builtin_amdgcn_sched_barrier(0);
    __builtin_amdgcn_s_barrier();
    __builtin_amdgcn_sched_barrier(0);
#pragma unroll
    for (int kt = 0; kt < 8; ++kt)
#pragma unroll
      for (int s = 0; s < 2; ++s) {
        v8s a0 = *(const v8s*)&lA[(size_t)((0 * 16 + kt) * 2 + s) * 512 + lane * 8];
        v8s a1 = *(const v8s*)&lA[(size_t)((1 * 16 + kt) * 2 + s) * 512 + lane * 8];
        acc[0][0] = mfma16(a0, breg[kt][s][0], acc[0][0]);
        acc[0][1] = mfma16(a0, breg[kt][s][1], acc[0][1]);
        acc[1][0] = mfma16(a1, breg[kt][s][0], acc[1][0]);
        acc[1][1] = mfma16(a1, breg[kt][s][1], acc[1][1]);
      }

    __builtin_amdgcn_sched_barrier(0);
    asm volatile("s_waitcnt vmcnt(0)" ::: "memory");   // h half1 landed
    __builtin_amdgcn_sched_barrier(0);
    __builtin_amdgcn_s_barrier();
    __builtin_amdgcn_sched_barrier(0);
#pragma unroll
    for (int kt = 8; kt < 16; ++kt)
#pragma unroll
      for (int s = 0; s < 2; ++s) {
        v8s a0 = *(const v8s*)&lA[(size_t)((0 * 16 + kt) * 2 + s) * 512 + lane * 8];
        v8s a1 = *(const v8s*)&lA[(size_t)((1 * 16 + kt) * 2 + s) * 512 + lane * 8];
        acc[0][0] = mfma16(a0, breg[kt][s][0], acc[0][0]);
        acc[0][1] = mfma16(a0, breg[kt][s][1], acc[0][1]);
        acc[1][0] = mfma16(a1, breg[kt][s][0], acc[1][0]);
        acc[1][1] = mfma16(a1, breg[kt][s][1], acc[1][1]);
      }

#pragma unroll
    for (int fm = 0; fm < 2; ++fm)
#pragma unroll
      for (int fn = 0; fn < 2; ++fn)
#pragma unroll
        for (int rg = 0; rg < 4; ++rg) {
          int rr = fm * 16 + ((lane >> 4) << 2) + rg;
          int cc = fn * 16 + (lane & 15);
          lact[wid][rr * 33 + cc] = acc[fm][fn][rg];
        }
    __syncthreads();

    // activations: gates = lact + base (+ W_begin at t=0)
    const float w0 = (t == 0) ? 1.f : 0.f;
    float m2a[4];
    u16 h2a[4];
#pragma unroll
    for (int q = 0; q < 4; ++q) {
      float gi = lact[0][rowm * 33 + nql + q] + ((const float*)&bse[0])[q] + w0 * ((const float*)&wbv[0])[q];
      float gf = lact[1][rowm * 33 + nql + q] + ((const float*)&bse[1])[q] + w0 * ((const float*)&wbv[1])[q];
      float gg = lact[2][rowm * 33 + nql + q] + ((const float*)&bse[2])[q] + w0 * ((const float*)&wbv[2])[q];
      float go = lact[3][rowm * 33 + nql + q] + ((const float*)&bse[3])[q] + w0 * ((const float*)&wbv[3])[q];
      float mov = ((const float*)&mreg)[q];
      float m2 = sigf(gf) * mov + sigf(gi) * tanhf_fast(gg);
      float h2 = sigf(go) * tanhf_fast(m2);
      m2a[q] = m2;
      h2a[q] = f2bf(h2);
    }
    mreg = make_float4(m2a[0], m2a[1], m2a[2], m2a[3]);
    ushort4 ho;
    ho.x = h2a[0]; ho.y = h2a[1]; ho.z = h2a[2]; ho.w = h2a[3];
    // coherent h-store: 8B relaxed agent atomic store (8B-aligned FP address)
    unsigned long long hv;
    __builtin_memcpy(&hv, &ho, 8);
    __hip_atomic_store(
        reinterpret_cast<unsigned long long*>(
            &hbuf[(size_t)(t + 1) * 262144 + fpoff(b, n, 16)]),
        hv, __ATOMIC_RELAXED, __HIP_MEMORY_SCOPE_AGENT);

    if (t < 15) {
      __syncthreads();  // drains vmcnt: all 4 waves' h-stores acked
      if (tid == 0)     // per-producer flag: plain store, no RMW
        __hip_atomic_store(&ctr[(t * 8 + grp) * 32 + n0idx], 1u,
                           __ATOMIC_RELAXED, __HIP_MEMORY_SCOPE_AGENT);
    }
  }
}

// ---------- kernel 6: batched FC + epilogue + mask ----------
__global__ __launch_bounds__(256) void k_fc(
    const u16* __restrict__ hall, const u16* __restrict__ wfcb,
    const float* __restrict__ bfc, const int* __restrict__ length,
    float* __restrict__ out) {
  __shared__ alignas(16) u16 lA[4 * 1024];
  __shared__ alignas(16) u16 lB[4 * 1024];
  const int tid = threadIdx.x, lane = tid & 63, wid = tid >> 6;
  const int bm0 = (int)(blockIdx.x % 64) * 64;
  const int bn0 = (int)(blockIdx.x / 64) * 64;  // grid 64*18
  const int wr = wid >> 1, wc = wid & 1;
  v4f acc[2][2];
#pragma unroll
  for (int i = 0; i < 2; ++i)
#pragma unroll
    for (int j = 0; j < 2; ++j) acc[i][j] = (v4f){0.f, 0.f, 0.f, 0.f};

  for (int kt = 0; kt < 16; ++kt) {
    const u16* asrc = hall + ((size_t)((bm0 >> 4) + wid) * 16 + kt) * 1024 + lane * 8;
    gll16(asrc, lA + wid * 1024);
    gll16(asrc + 512, lA + wid * 1024 + 512);
    const u16* bsrc = wfcb + ((size_t)((bn0 >> 4) + wid) * 16 + kt) * 1024 + lane * 8;
    gll16(bsrc, lB + wid * 1024);
    gll16(bsrc + 512, lB + wid * 1024 + 512);
    __syncthreads();
#pragma unroll
    for (int s = 0; s < 2; ++s) {
      v8s a0 = *(const v8s*)&lA[(size_t)(wr * 2) * 1024 + s * 512 + lane * 8];
      v8s a1 = *(const v8s*)&lA[(size_t)(wr * 2 + 1) * 1024 + s * 512 + lane * 8];
      v8s b0 = *(const v8s*)&lB[(size_t)(wc * 2) * 1024 + s * 512 + lane * 8];
      v8s b1 = *(const v8s*)&lB[(size_t)(wc * 2 + 1) * 1024 + s * 512 + lane * 8];
      acc[0][0] = mfma16(a0, b0, acc[0][0]);
      acc[0][1] = mfma16(a0, b1, acc[0][1]);
      acc[1][0] = mfma16(a1, b0, acc[1][0]);
      acc[1][1] = mfma16(a1, b1, acc[1][1]);
    }
    __syncthreads();
  }
#pragma unroll
  for (int fm = 0; fm < 2; ++fm)
#pragma unroll
    for (int fn = 0; fn < 2; ++fn)
#pragma unroll
      for (int rg = 0; rg < 4; ++rg) {
        int r = bm0 + wr * 32 + fm * 16 + ((lane >> 4) << 2) + rg;
        int j = bn0 + wc * 32 + fn * 16 + (lane & 15);
        if (j < 64 || j >= 1090) continue;
        int t = r >> 8, b = r & 255;
        float v = acc[fm][fn][rg] + bfc[j];
        int c;
        if (j < 1088) { c = j - 64; v = fmaxf(v, 0.f); }
        else if (j == 1088) { c = 1024; v = 1.f / (1.f + expf(-v)); }
        else { c = 1025; v = expf(v); }
        if (t >= length[b] - 1) v = 0.f;
        out[((size_t)t * 256 + b) * 1026 + c] = v;
      }
}

extern "C" void kernel_launch(void* const* d_in, const int* in_sizes, int n_in,
                              void* d_out, int out_size, void* d_ws, size_t ws_size,
                              hipStream_t stream) {
  (void)in_sizes; (void)n_in; (void)out_size; (void)ws_size;
  const float* image  = (const float*)d_in[0];
  const float* vp     = (const float*)d_in[1];
  const float* label  = (const float*)d_in[2];
  const int*   length = (const int*)d_in[3];
  const float* Wh  = (const float*)d_in[4];
  const float* bh  = (const float*)d_in[5];
  const float* Wm  = (const float*)d_in[6];
  const float* bm  = (const float*)d_in[7];
  const float* Wih = (const float*)d_in[8];
  const float* Whh = (const float*)d_in[9];
  const float* bih = (const float*)d_in[10];
  const float* bhh = (const float*)d_in[11];
  const float* Wfc = (const float*)d_in[12];
  const float* bfc = (const float*)d_in[13];
  float* out = (float*)d_out;
  char* ws = (char*)d_ws;

  size_t off = 0;
  u16* wcomb  = (u16*)(ws + off); off += (size_t)6144 * 1024 * 2;
  u16* whhb   = (u16*)(ws + off); off += (size_t)4096 * 1024 * 2;
  u16* wfcb   = (u16*)(ws + off); off += (size_t)1152 * 1024 * 2;
  u16* wlabb  = (u16*)(ws + off); off += (size_t)4096 * 64 * 2;
  u16* labb   = (u16*)(ws + off); off += (size_t)4096 * 64 * 2;
  u16* meanbf = (u16*)(ws + off); off += (size_t)256 * 1024 * 2;
  u16* hbuf   = (u16*)(ws + off); off += (size_t)17 * 256 * 1024 * 2;
  float* mbuf    = (float*)(ws + off); off += (size_t)256 * 1024 * 4;
  float* basebuf = (float*)(ws + off); off += (size_t)256 * 4096 * 4;
  unsigned* ctr = (unsigned*)(ws + off); off += 4096 * 4;
  float4* pacc = (float4*)(ws + off); off += (size_t)2048 * 256 * 16;

  k_convert_mean<<<8016, 256, 0, stream>>>(Wh, Wm, Wih, Whh, Wfc, label, image,
                                           wcomb, whhb, wfcb, wlabb, labb, pacc, ctr);
  k_mean2<<<256, 256, 0, stream>>>(pacc, meanbf);
  k_gemm_init<<<384, 256, 0, stream>>>(meanbf, wcomb, bh, bm, bih, bhh, vp, Wih,
                                       hbuf, mbuf, basebuf);
  k_steps<<<256, 256, 0, stream>>>(whhb, wlabb, labb, basebuf, Wih, mbuf, hbuf, ctr);
  k_fc<<<1152, 256, 0, stream>>>(hbuf + (size_t)256 * 1024, wfcb, bfc, length, out);
}